// Round 13
// baseline (105.262 us; speedup 1.0000x reference)
//
#include <hip/hip_runtime.h>
#include <math.h>

// ContextualLoss via MFMA bf16.
// X,T = reshape(50,16384)[10:50]; S = Xn^T Tn (K=40 padded to 64, bf16 MFMA);
// per input-column i: m=min_j S, M=max_j S, Z=sum_j exp((1-S/(m+eps))/h);
// CXmax_i = max(w(m),w(M))/Z (w monotone in S); loss = -log(max_i CXmax_i).
//
// R12 = R11 + (a) MI_T 4->2 (32 rows/wave) to drop VGPR below the 8-waves/
// SIMD bucket (evidence: VGPR=64 kernels pin at <=42% occupancy at any grid
// size; R9's VGPR=44 hit 58%); safe now because B comes from LDS, killing
// R9's global-load-amortization failure; (b) staging via
// __builtin_amdgcn_global_load_lds with the slot^(row&7) swizzle PRE-BAKED
// into tb's global layout (m173 pattern: linear LDS dest + inverse-swizzled
// source + swizzled read) -- deletes st[] regs (-16 VGPR) and staging VALU.

#define NCOL   16384
#define KDIM   40
#define KPAD   64
#define ROW0   10
#define EPSILON 1e-5f
#define COS_EPS 1e-8f
#define Q5L2E   7.2134752044448169f   // 5 * log2(e)  (1/h = 5)
#define JS      16                    // j slices
#define JSL     (NCOL / JS)           // 1024 j per slice
#define CHJ     64                    // j per staged chunk (8 KB)
#define NCH     (JSL / CHJ)           // 16 chunks per slice
#define TPC     (CHJ / 16)            // 4 16-wide j tiles per chunk
#define MI_T    2                     // 16-row M-subtiles per wave
#define RPB     (MI_T * 16 * 4)       // rows per block = 128
#define IBLK    (NCOL / RPB)          // 128 i-blocks

#if __has_builtin(__builtin_amdgcn_exp2f)
#define EXP2F(x) __builtin_amdgcn_exp2f(x)
#else
#define EXP2F(x) __expf((x) * 0.69314718055994531f)
#endif

// async global->LDS, 16B/lane, LDS dest = wave-uniform base + lane*16
#define GLL16(g, l)                                                           \
    __builtin_amdgcn_global_load_lds(                                         \
        (const __attribute__((address_space(1))) void*)(const void*)(g),      \
        (__attribute__((address_space(3))) void*)(void*)(l), 16, 0, 0)

typedef __attribute__((ext_vector_type(8))) short bf16x8;
typedef __attribute__((ext_vector_type(4))) float f32x4;

static __device__ __forceinline__ unsigned short f2bf(float f) {
    unsigned u = __float_as_uint(f);           // RNE float->bf16
    u += 0x7FFFu + ((u >> 16) & 1u);
    return (unsigned short)(u >> 16);
}

// ---------------- kernel 1: mu + column normalize + bf16 pack ----------------
// xb: linear [n][64]. tb: SWIZZLED [n][slot^(n&7)] so that a linear
// global_load_lds copy reproduces the bank-conflict-free LDS layout.
__global__ __launch_bounds__(256) void ctx_norm_kernel(
        const float* __restrict__ inp, const float* __restrict__ tgt,
        short* __restrict__ xb, short* __restrict__ tb) {
    int n = blockIdx.x * 256 + threadIdx.x;
    float t[KDIM], x[KDIM];
    float mu = 0.f;
#pragma unroll
    for (int r = 0; r < KDIM; ++r) { t[r] = tgt[(ROW0 + r) * NCOL + n]; mu += t[r]; }
    mu *= (1.0f / KDIM);
    float nt = 0.f;
#pragma unroll
    for (int r = 0; r < KDIM; ++r) { t[r] -= mu; nt = fmaf(t[r], t[r], nt); }
    float rnt = 1.0f / fmaxf(sqrtf(nt), COS_EPS);
    float nx = 0.f;
#pragma unroll
    for (int r = 0; r < KDIM; ++r) {
        x[r] = inp[(ROW0 + r) * NCOL + n] - mu;
        nx = fmaf(x[r], x[r], nx);
    }
    float rnx = 1.0f / fmaxf(sqrtf(nx), COS_EPS);

    short* to = tb + (size_t)n * KPAD;
    short* xo = xb + (size_t)n * KPAD;
    const int sw = n & 7;
#pragma unroll
    for (int q = 0; q < KDIM / 4; ++q) {        // q = 0..9: data
        ushort4 wt, wx;
        wt.x = f2bf(t[4*q+0] * rnt); wt.y = f2bf(t[4*q+1] * rnt);
        wt.z = f2bf(t[4*q+2] * rnt); wt.w = f2bf(t[4*q+3] * rnt);
        wx.x = f2bf(x[4*q+0] * rnx); wx.y = f2bf(x[4*q+1] * rnx);
        wx.z = f2bf(x[4*q+2] * rnx); wx.w = f2bf(x[4*q+3] * rnx);
        int p_ = ((q >> 1) ^ sw);               // 16B slot swizzle
        *reinterpret_cast<ushort4*>(to + p_ * 8 + (q & 1) * 4) = wt;
        *reinterpret_cast<ushort4*>(xo + 4 * q) = wx;
    }
    ushort4 z = {0, 0, 0, 0};
#pragma unroll
    for (int q = KDIM / 4; q < KPAD / 4; ++q) { // q = 10..15: zero pad
        int p_ = ((q >> 1) ^ sw);
        *reinterpret_cast<ushort4*>(to + p_ * 8 + (q & 1) * 4) = z;
        *reinterpret_cast<ushort4*>(xo + 4 * q) = z;
    }
}

// ---------------- kernel 2: MFMA row min/max over a j slice ----------------
// grid (IBLK, JS), 256 thr = 4 waves. Wave owns 32 i-rows (2 M-subtiles).
// B double-buffered in LDS via global_load_lds (linear copy of pre-swizzled
// tb). Read swizzle: slot = g ^ (row&7). C/D: col=lane&15, row=(lane>>4)*4+r.
__global__ __launch_bounds__(256) void ctx_stats_kernel(
        const short* __restrict__ xb, const short* __restrict__ tb,
        float* __restrict__ pmin, float* __restrict__ pmax) {
    const int tid = threadIdx.x;
    const int wave = tid >> 6, l = tid & 63;
    const int la = l & 15, g = l >> 4;
    const int ibase = blockIdx.x * RPB + wave * (MI_T * 16);
    const int js = blockIdx.y;

    __shared__ __align__(16) short ldsb[2][CHJ * KPAD];   // 2 x 8 KB

    bf16x8 a[MI_T][2];
#pragma unroll
    for (int mi = 0; mi < MI_T; ++mi)
#pragma unroll
        for (int ks = 0; ks < 2; ++ks)
            a[mi][ks] = *reinterpret_cast<const bf16x8*>(
                xb + (size_t)(ibase + mi * 16 + la) * KPAD + ks * 32 + g * 8);

    float vmn[MI_T][4], vmx[MI_T][4];
#pragma unroll
    for (int mi = 0; mi < MI_T; ++mi)
#pragma unroll
        for (int r = 0; r < 4; ++r) { vmn[mi][r] = 3.4e38f; vmx[mi][r] = -3.4e38f; }

    const short* tbase = tb + (size_t)js * JSL * KPAD;

    {   // prologue: stage chunk 0 into buffer 0 (2 x 16B per thread)
        const short* gs = tbase + tid * 8;
        short* ls = &ldsb[0][wave * 512];
        GLL16(gs, ls); GLL16(gs + 2048, ls + 2048);
    }
    __syncthreads();

    const f32x4 zero4 = {0.f, 0.f, 0.f, 0.f};
    int cb = 0;
    for (int ch = 0; ch < NCH; ++ch) {
        if (ch + 1 < NCH) {               // issue next-chunk DMA early
            const short* gs = tbase + (size_t)(ch + 1) * CHJ * KPAD + tid * 8;
            short* ls = &ldsb[cb ^ 1][wave * 512];
            GLL16(gs, ls); GLL16(gs + 2048, ls + 2048);
        }
#pragma unroll 2
        for (int jj = 0; jj < TPC; ++jj) {
            const int lr = jj * 16 + la;
            const short* lp = &ldsb[cb][lr * 64];
            bf16x8 b0 = *reinterpret_cast<const bf16x8*>(lp + ((g    ) ^ (lr & 7)) * 8);
            bf16x8 b1 = *reinterpret_cast<const bf16x8*>(lp + ((g + 4) ^ (lr & 7)) * 8);
#pragma unroll
            for (int mi = 0; mi < MI_T; ++mi) {
                f32x4 acc = __builtin_amdgcn_mfma_f32_16x16x32_bf16(a[mi][0], b0, zero4, 0, 0, 0);
                acc = __builtin_amdgcn_mfma_f32_16x16x32_bf16(a[mi][1], b1, acc, 0, 0, 0);
#pragma unroll
                for (int r = 0; r < 4; ++r) {
                    vmn[mi][r] = fminf(vmn[mi][r], acc[r]);
                    vmx[mi][r] = fmaxf(vmx[mi][r], acc[r]);
                }
            }
        }
        __syncthreads();                  // drains DMA (vmcnt) + sync readers
        cb ^= 1;
    }

    // reduce over the 16 column-lanes of each 16-lane group
#pragma unroll
    for (int off = 1; off < 16; off <<= 1)
#pragma unroll
        for (int mi = 0; mi < MI_T; ++mi)
#pragma unroll
            for (int r = 0; r < 4; ++r) {
                vmn[mi][r] = fminf(vmn[mi][r], __shfl_xor(vmn[mi][r], off, 64));
                vmx[mi][r] = fmaxf(vmx[mi][r], __shfl_xor(vmx[mi][r], off, 64));
            }
    if (la == 0) {
#pragma unroll
        for (int mi = 0; mi < MI_T; ++mi)
#pragma unroll
            for (int r = 0; r < 4; ++r) {
                int row = ibase + mi * 16 + g * 4 + r;
                pmin[js * NCOL + row] = vmn[mi][r];
                pmax[js * NCOL + row] = vmx[mi][r];
            }
    }
}

// ---------------- kernel 3: fold JS partials -> final row min/max ----------------
__global__ __launch_bounds__(256) void ctx_fold_kernel(
        const float* __restrict__ pmin, const float* __restrict__ pmax,
        float* __restrict__ rmin, float* __restrict__ rmax) {
    int i = blockIdx.x * 256 + threadIdx.x;
    float m = pmin[i], M = pmax[i];
#pragma unroll
    for (int s = 1; s < JS; ++s) {
        m = fminf(m, pmin[s * NCOL + i]);
        M = fmaxf(M, pmax[s * NCOL + i]);
    }
    rmin[i] = m; rmax[i] = M;
}

// ---------------- kernel 4: MFMA row sum of exp over a j slice ----------------
// w = exp((1-S*c)/h) = exp2(fma(S, -Q5L2E*c, Q5L2E)), c = 1/(m+eps) per row.
__global__ __launch_bounds__(256) void ctx_sumexp_kernel(
        const short* __restrict__ xb, const short* __restrict__ tb,
        const float* __restrict__ rmin, float* __restrict__ psum) {
    const int tid = threadIdx.x;
    const int wave = tid >> 6, l = tid & 63;
    const int la = l & 15, g = l >> 4;
    const int ibase = blockIdx.x * RPB + wave * (MI_T * 16);
    const int js = blockIdx.y;

    __shared__ __align__(16) short ldsb[2][CHJ * KPAD];   // 2 x 8 KB

    bf16x8 a[MI_T][2];
#pragma unroll
    for (int mi = 0; mi < MI_T; ++mi)
#pragma unroll
        for (int ks = 0; ks < 2; ++ks)
            a[mi][ks] = *reinterpret_cast<const bf16x8*>(
                xb + (size_t)(ibase + mi * 16 + la) * KPAD + ks * 32 + g * 8);

    float p[MI_T][4], zs[MI_T][4];
#pragma unroll
    for (int mi = 0; mi < MI_T; ++mi)
#pragma unroll
        for (int r = 0; r < 4; ++r) {
            int row = ibase + mi * 16 + g * 4 + r;
            float c = 1.0f / (rmin[row] + EPSILON);
            p[mi][r] = -Q5L2E * c;
            zs[mi][r] = 0.f;
        }

    const short* tbase = tb + (size_t)js * JSL * KPAD;

    {   // prologue: stage chunk 0 into buffer 0
        const short* gs = tbase + tid * 8;
        short* ls = &ldsb[0][wave * 512];
        GLL16(gs, ls); GLL16(gs + 2048, ls + 2048);
    }
    __syncthreads();

    const f32x4 zero4 = {0.f, 0.f, 0.f, 0.f};
    int cb = 0;
    for (int ch = 0; ch < NCH; ++ch) {
        if (ch + 1 < NCH) {               // issue next-chunk DMA early
            const short* gs = tbase + (size_t)(ch + 1) * CHJ * KPAD + tid * 8;
            short* ls = &ldsb[cb ^ 1][wave * 512];
            GLL16(gs, ls); GLL16(gs + 2048, ls + 2048);
        }
#pragma unroll 2
        for (int jj = 0; jj < TPC; ++jj) {
            const int lr = jj * 16 + la;
            const short* lp = &ldsb[cb][lr * 64];
            bf16x8 b0 = *reinterpret_cast<const bf16x8*>(lp + ((g    ) ^ (lr & 7)) * 8);
            bf16x8 b1 = *reinterpret_cast<const bf16x8*>(lp + ((g + 4) ^ (lr & 7)) * 8);
#pragma unroll
            for (int mi = 0; mi < MI_T; ++mi) {
                f32x4 acc = __builtin_amdgcn_mfma_f32_16x16x32_bf16(a[mi][0], b0, zero4, 0, 0, 0);
                acc = __builtin_amdgcn_mfma_f32_16x16x32_bf16(a[mi][1], b1, acc, 0, 0, 0);
#pragma unroll
                for (int r = 0; r < 4; ++r)
                    zs[mi][r] += EXP2F(fmaf(acc[r], p[mi][r], Q5L2E));
            }
        }
        __syncthreads();
        cb ^= 1;
    }

#pragma unroll
    for (int off = 1; off < 16; off <<= 1)
#pragma unroll
        for (int mi = 0; mi < MI_T; ++mi)
#pragma unroll
            for (int r = 0; r < 4; ++r)
                zs[mi][r] += __shfl_xor(zs[mi][r], off, 64);
    if (la == 0) {
#pragma unroll
        for (int mi = 0; mi < MI_T; ++mi)
#pragma unroll
            for (int r = 0; r < 4; ++r) {
                int row = ibase + mi * 16 + g * 4 + r;
                psum[js * NCOL + row] = zs[mi][r];
            }
    }
}

// ---------------- kernel 5: per-row CX-max, per-block max ----------------
__global__ __launch_bounds__(256) void ctx_reduce_kernel(
        const float* __restrict__ rmin, const float* __restrict__ rmax,
        const float* __restrict__ psum, float* __restrict__ blkmax) {
    int tid = threadIdx.x;
    int i = blockIdx.x * 256 + tid;
    float m = rmin[i], M = rmax[i], Z = psum[i];
#pragma unroll
    for (int s = 1; s < JS; ++s) Z += psum[s * NCOL + i];
    float c = 1.0f / (m + EPSILON);
    float w1 = EXP2F(fmaf(M, -Q5L2E * c, Q5L2E));
    float w2 = EXP2F(fmaf(m, -Q5L2E * c, Q5L2E));
    float best = fmaxf(w1, w2) / Z;   // CX strictly positive

    for (int off = 32; off > 0; off >>= 1)
        best = fmaxf(best, __shfl_down(best, off, 64));
    __shared__ float red[4];
    if ((tid & 63) == 0) red[tid >> 6] = best;
    __syncthreads();
    if (tid == 0)
        blkmax[blockIdx.x] = fmaxf(fmaxf(red[0], red[1]), fmaxf(red[2], red[3]));
}

// ---------------- kernel 6: 64 -> 1, -log ----------------
__global__ void ctx_loss_kernel(const float* __restrict__ blkmax,
                                float* __restrict__ out) {
    int tid = threadIdx.x;       // one wave of 64
    float best = blkmax[tid];
    for (int off = 32; off > 0; off >>= 1)
        best = fmaxf(best, __shfl_down(best, off, 64));
    if (tid == 0) out[0] = -logf(best);
}

extern "C" void kernel_launch(void* const* d_in, const int* in_sizes, int n_in,
                              void* d_out, int out_size, void* d_ws, size_t ws_size,
                              hipStream_t stream) {
    const float* inp = (const float*)d_in[0];
    const float* tgt = (const float*)d_in[1];
    float* out = (float*)d_out;

    // ws layout (bytes):
    //   xb     bf16 [16384][64]  2 MB   (linear)
    //   tb     bf16 [16384][64]  2 MB   (slot-swizzled layout)
    //   pmin   f32  [16][16384]  1 MB
    //   pmax   f32  [16][16384]  1 MB
    //   psum   f32  [16][16384]  1 MB
    //   rmin   f32  [16384]      64 KB
    //   rmax   f32  [16384]      64 KB
    //   blkmax f32  [64]
    char* base = (char*)d_ws;
    short* xb     = (short*)(base);
    short* tb     = (short*)(base + (size_t)2 * NCOL * KPAD);           // +2MB
    float* pmin   = (float*)(base + (size_t)4 * NCOL * KPAD);           // +4MB
    float* pmax   = pmin + (size_t)JS * NCOL;
    float* psum   = pmax + (size_t)JS * NCOL;
    float* rmin   = psum + (size_t)JS * NCOL;
    float* rmax   = rmin + NCOL;
    float* blkmax = rmax + NCOL;

    dim3 grid2(IBLK, JS);
    ctx_norm_kernel  <<<NCOL / 256, 256, 0, stream>>>(inp, tgt, xb, tb);
    ctx_stats_kernel <<<grid2, 256, 0, stream>>>(xb, tb, pmin, pmax);
    ctx_fold_kernel  <<<NCOL / 256, 256, 0, stream>>>(pmin, pmax, rmin, rmax);
    ctx_sumexp_kernel<<<grid2, 256, 0, stream>>>(xb, tb, rmin, psum);
    ctx_reduce_kernel<<<NCOL / 256, 256, 0, stream>>>(rmin, rmax, psum, blkmax);
    ctx_loss_kernel  <<<1, 64, 0, stream>>>(blkmax, out);
}

// Round 14
// 101.764 us; speedup vs baseline: 1.0344x; 1.0344x over previous
//
#include <hip/hip_runtime.h>
#include <math.h>

// ContextualLoss via MFMA bf16.
// X,T = reshape(50,16384)[10:50]; S = Xn^T Tn (K=40 padded to 64, bf16 MFMA);
// per input-column i: m=min_j S, M=max_j S, Z=sum_j exp((1-S/(m+eps))/h);
// CXmax_i = max(w(m),w(M))/Z (w monotone in S); loss = -log(max_i CXmax_i).
//
// R14 = R11 tiling (MI_T=4: 64 rows/wave, 256 rows/block, grid (64,16)) +
// gll staging of pre-swizzled tb (R12-validated) + T3/T4 pipeline:
// 3 LDS buffers (CHJ=64, 8KB each), depth-2 prefetch, raw s_barrier +
// counted s_waitcnt vmcnt(2) -- never vmcnt(0) in steady state, so the
// prefetch DMA stays in flight across the barrier (kills the __syncthreads
// vmcnt(0) drain that stalled R11's lockstep loop). R13 lesson: MI_T=2
// doubles B-staging per output -> regression; occupancy axis is dead
// (R8/R9/R12), amortization + sync are the live axes.
//
// Pipeline protocol (per wave, uniform control flow):
//   prologue: issue gll(c0)->buf0, gll(c1)->buf1          [4 outstanding]
//   iter c:   s_waitcnt vmcnt(2)   // c's DMA done, c+1's in flight
//             s_barrier            // all waves' c-DMA done
//             compute buf[c%3]
//             issue gll(c+2)->buf[(c+2)%3]   // readers of that buf finished
//                                            // at iter c-1 (barrier-proven)

#define NCOL   16384
#define KDIM   40
#define KPAD   64
#define ROW0   10
#define EPSILON 1e-5f
#define COS_EPS 1e-8f
#define Q5L2E   7.2134752044448169f   // 5 * log2(e)  (1/h = 5)
#define JS      16                    // j slices
#define JSL     (NCOL / JS)           // 1024 j per slice
#define CHJ     64                    // j per staged chunk (8 KB)
#define NCH     (JSL / CHJ)           // 16 chunks per slice
#define TPC     (CHJ / 16)            // 4 16-wide j tiles per chunk

#if __has_builtin(__builtin_amdgcn_exp2f)
#define EXP2F(x) __builtin_amdgcn_exp2f(x)
#else
#define EXP2F(x) __expf((x) * 0.69314718055994531f)
#endif

// async global->LDS, 16B/lane, LDS dest = wave-uniform base + lane*16
#define GLL16(g, l)                                                           \
    __builtin_amdgcn_global_load_lds(                                         \
        (const __attribute__((address_space(1))) void*)(const void*)(g),      \
        (__attribute__((address_space(3))) void*)(void*)(l), 16, 0, 0)

typedef __attribute__((ext_vector_type(8))) short bf16x8;
typedef __attribute__((ext_vector_type(4))) float f32x4;

static __device__ __forceinline__ unsigned short f2bf(float f) {
    unsigned u = __float_as_uint(f);           // RNE float->bf16
    u += 0x7FFFu + ((u >> 16) & 1u);
    return (unsigned short)(u >> 16);
}

// ---------------- kernel 1: mu + column normalize + bf16 pack ----------------
// xb: linear [n][64]. tb: SWIZZLED [n][slot^(n&7)] so a linear global_load_lds
// copy reproduces the bank-conflict-free LDS layout (m173 pattern).
__global__ __launch_bounds__(256) void ctx_norm_kernel(
        const float* __restrict__ inp, const float* __restrict__ tgt,
        short* __restrict__ xb, short* __restrict__ tb) {
    int n = blockIdx.x * 256 + threadIdx.x;
    float t[KDIM], x[KDIM];
    float mu = 0.f;
#pragma unroll
    for (int r = 0; r < KDIM; ++r) { t[r] = tgt[(ROW0 + r) * NCOL + n]; mu += t[r]; }
    mu *= (1.0f / KDIM);
    float nt = 0.f;
#pragma unroll
    for (int r = 0; r < KDIM; ++r) { t[r] -= mu; nt = fmaf(t[r], t[r], nt); }
    float rnt = 1.0f / fmaxf(sqrtf(nt), COS_EPS);
    float nx = 0.f;
#pragma unroll
    for (int r = 0; r < KDIM; ++r) {
        x[r] = inp[(ROW0 + r) * NCOL + n] - mu;
        nx = fmaf(x[r], x[r], nx);
    }
    float rnx = 1.0f / fmaxf(sqrtf(nx), COS_EPS);

    short* to = tb + (size_t)n * KPAD;
    short* xo = xb + (size_t)n * KPAD;
    const int sw = n & 7;
#pragma unroll
    for (int q = 0; q < KDIM / 4; ++q) {        // q = 0..9: data
        ushort4 wt, wx;
        wt.x = f2bf(t[4*q+0] * rnt); wt.y = f2bf(t[4*q+1] * rnt);
        wt.z = f2bf(t[4*q+2] * rnt); wt.w = f2bf(t[4*q+3] * rnt);
        wx.x = f2bf(x[4*q+0] * rnx); wx.y = f2bf(x[4*q+1] * rnx);
        wx.z = f2bf(x[4*q+2] * rnx); wx.w = f2bf(x[4*q+3] * rnx);
        int p_ = ((q >> 1) ^ sw);               // 16B slot swizzle
        *reinterpret_cast<ushort4*>(to + p_ * 8 + (q & 1) * 4) = wt;
        *reinterpret_cast<ushort4*>(xo + 4 * q) = wx;
    }
    ushort4 z = {0, 0, 0, 0};
#pragma unroll
    for (int q = KDIM / 4; q < KPAD / 4; ++q) { // q = 10..15: zero pad
        int p_ = ((q >> 1) ^ sw);
        *reinterpret_cast<ushort4*>(to + p_ * 8 + (q & 1) * 4) = z;
        *reinterpret_cast<ushort4*>(xo + 4 * q) = z;
    }
}

// issue one chunk's DMA: 2 x 16B per thread (8 KB chunk / 256 thr)
#define ISSUE_CHUNK(gsrc, lbuf)                                               \
    {                                                                         \
        const short* gs_ = (gsrc) + tid * 8;                                  \
        short* ls_ = (lbuf) + wave * 512;                                     \
        GLL16(gs_, ls_); GLL16(gs_ + 2048, ls_ + 2048);                       \
    }

// ---------------- kernel 2: MFMA row min/max over a j slice ----------------
// grid (64, JS), 256 thr = 4 waves. Wave owns 64 i-rows (4 MFMA M-subtiles).
// B via 3-buffer gll pipeline. Read swizzle: slot = g ^ (row&7).
// C/D: col=lane&15, row=(lane>>4)*4+reg.
__global__ __launch_bounds__(256, 4) void ctx_stats_kernel(
        const short* __restrict__ xb, const short* __restrict__ tb,
        float* __restrict__ pmin, float* __restrict__ pmax) {
    const int tid = threadIdx.x;
    const int wave = tid >> 6, l = tid & 63;
    const int la = l & 15, g = l >> 4;
    const int ibase = blockIdx.x * 256 + wave * 64;
    const int js = blockIdx.y;

    __shared__ __align__(16) short ldsb[3][CHJ * KPAD];   // 3 x 8 KB

    bf16x8 a[4][2];
#pragma unroll
    for (int mi = 0; mi < 4; ++mi)
#pragma unroll
        for (int ks = 0; ks < 2; ++ks)
            a[mi][ks] = *reinterpret_cast<const bf16x8*>(
                xb + (size_t)(ibase + mi * 16 + la) * KPAD + ks * 32 + g * 8);

    float vmn[4][4], vmx[4][4];
#pragma unroll
    for (int mi = 0; mi < 4; ++mi)
#pragma unroll
        for (int r = 0; r < 4; ++r) { vmn[mi][r] = 3.4e38f; vmx[mi][r] = -3.4e38f; }

    const short* tbase = tb + (size_t)js * JSL * KPAD;
    short* bA = &ldsb[0][0];
    short* bB = &ldsb[1][0];
    short* bC = &ldsb[2][0];

    ISSUE_CHUNK(tbase, bA);                       // chunk 0
    ISSUE_CHUNK(tbase + CHJ * KPAD, bB);          // chunk 1

    const f32x4 zero4 = {0.f, 0.f, 0.f, 0.f};
    for (int ch = 0; ch < NCH; ++ch) {
        if (ch < NCH - 1) asm volatile("s_waitcnt vmcnt(2)" ::: "memory");
        else              asm volatile("s_waitcnt vmcnt(0)" ::: "memory");
        __builtin_amdgcn_s_barrier();             // all waves' ch-DMA landed
        __builtin_amdgcn_sched_barrier(0);
#pragma unroll
        for (int jj = 0; jj < TPC; ++jj) {
            const int lr = jj * 16 + la;
            const short* lp = bA + lr * 64;
            bf16x8 b0 = *reinterpret_cast<const bf16x8*>(lp + ((g    ) ^ (lr & 7)) * 8);
            bf16x8 b1 = *reinterpret_cast<const bf16x8*>(lp + ((g + 4) ^ (lr & 7)) * 8);
#pragma unroll
            for (int mi = 0; mi < 4; ++mi) {
                f32x4 acc = __builtin_amdgcn_mfma_f32_16x16x32_bf16(a[mi][0], b0, zero4, 0, 0, 0);
                acc = __builtin_amdgcn_mfma_f32_16x16x32_bf16(a[mi][1], b1, acc, 0, 0, 0);
#pragma unroll
                for (int r = 0; r < 4; ++r) {
                    vmn[mi][r] = fminf(vmn[mi][r], acc[r]);
                    vmx[mi][r] = fmaxf(vmx[mi][r], acc[r]);
                }
            }
        }
        __builtin_amdgcn_sched_barrier(0);        // pin issue after compute
        if (ch + 2 < NCH)
            ISSUE_CHUNK(tbase + (size_t)(ch + 2) * CHJ * KPAD, bC);
        short* tp = bA; bA = bB; bB = bC; bC = tp; // rotate buffers
    }

    // reduce over the 16 column-lanes of each 16-lane group
#pragma unroll
    for (int off = 1; off < 16; off <<= 1)
#pragma unroll
        for (int mi = 0; mi < 4; ++mi)
#pragma unroll
            for (int r = 0; r < 4; ++r) {
                vmn[mi][r] = fminf(vmn[mi][r], __shfl_xor(vmn[mi][r], off, 64));
                vmx[mi][r] = fmaxf(vmx[mi][r], __shfl_xor(vmx[mi][r], off, 64));
            }
    if (la == 0) {
#pragma unroll
        for (int mi = 0; mi < 4; ++mi)
#pragma unroll
            for (int r = 0; r < 4; ++r) {
                int row = ibase + mi * 16 + g * 4 + r;
                pmin[js * NCOL + row] = vmn[mi][r];
                pmax[js * NCOL + row] = vmx[mi][r];
            }
    }
}

// ---------------- kernel 3: fold JS partials -> final row min/max ----------------
__global__ __launch_bounds__(256) void ctx_fold_kernel(
        const float* __restrict__ pmin, const float* __restrict__ pmax,
        float* __restrict__ rmin, float* __restrict__ rmax) {
    int i = blockIdx.x * 256 + threadIdx.x;
    float m = pmin[i], M = pmax[i];
#pragma unroll
    for (int s = 1; s < JS; ++s) {
        m = fminf(m, pmin[s * NCOL + i]);
        M = fmaxf(M, pmax[s * NCOL + i]);
    }
    rmin[i] = m; rmax[i] = M;
}

// ---------------- kernel 4: MFMA row sum of exp over a j slice ----------------
// w = exp((1-S*c)/h) = exp2(fma(S, -Q5L2E*c, Q5L2E)), c = 1/(m+eps) per row.
__global__ __launch_bounds__(256, 4) void ctx_sumexp_kernel(
        const short* __restrict__ xb, const short* __restrict__ tb,
        const float* __restrict__ rmin, float* __restrict__ psum) {
    const int tid = threadIdx.x;
    const int wave = tid >> 6, l = tid & 63;
    const int la = l & 15, g = l >> 4;
    const int ibase = blockIdx.x * 256 + wave * 64;
    const int js = blockIdx.y;

    __shared__ __align__(16) short ldsb[3][CHJ * KPAD];   // 3 x 8 KB

    bf16x8 a[4][2];
#pragma unroll
    for (int mi = 0; mi < 4; ++mi)
#pragma unroll
        for (int ks = 0; ks < 2; ++ks)
            a[mi][ks] = *reinterpret_cast<const bf16x8*>(
                xb + (size_t)(ibase + mi * 16 + la) * KPAD + ks * 32 + g * 8);

    float p[4][4], zs[4][4];
#pragma unroll
    for (int mi = 0; mi < 4; ++mi)
#pragma unroll
        for (int r = 0; r < 4; ++r) {
            int row = ibase + mi * 16 + g * 4 + r;
            float c = 1.0f / (rmin[row] + EPSILON);
            p[mi][r] = -Q5L2E * c;
            zs[mi][r] = 0.f;
        }

    const short* tbase = tb + (size_t)js * JSL * KPAD;
    short* bA = &ldsb[0][0];
    short* bB = &ldsb[1][0];
    short* bC = &ldsb[2][0];

    ISSUE_CHUNK(tbase, bA);                       // chunk 0
    ISSUE_CHUNK(tbase + CHJ * KPAD, bB);          // chunk 1

    const f32x4 zero4 = {0.f, 0.f, 0.f, 0.f};
    for (int ch = 0; ch < NCH; ++ch) {
        if (ch < NCH - 1) asm volatile("s_waitcnt vmcnt(2)" ::: "memory");
        else              asm volatile("s_waitcnt vmcnt(0)" ::: "memory");
        __builtin_amdgcn_s_barrier();
        __builtin_amdgcn_sched_barrier(0);
#pragma unroll
        for (int jj = 0; jj < TPC; ++jj) {
            const int lr = jj * 16 + la;
            const short* lp = bA + lr * 64;
            bf16x8 b0 = *reinterpret_cast<const bf16x8*>(lp + ((g    ) ^ (lr & 7)) * 8);
            bf16x8 b1 = *reinterpret_cast<const bf16x8*>(lp + ((g + 4) ^ (lr & 7)) * 8);
#pragma unroll
            for (int mi = 0; mi < 4; ++mi) {
                f32x4 acc = __builtin_amdgcn_mfma_f32_16x16x32_bf16(a[mi][0], b0, zero4, 0, 0, 0);
                acc = __builtin_amdgcn_mfma_f32_16x16x32_bf16(a[mi][1], b1, acc, 0, 0, 0);
#pragma unroll
                for (int r = 0; r < 4; ++r)
                    zs[mi][r] += EXP2F(fmaf(acc[r], p[mi][r], Q5L2E));
            }
        }
        __builtin_amdgcn_sched_barrier(0);
        if (ch + 2 < NCH)
            ISSUE_CHUNK(tbase + (size_t)(ch + 2) * CHJ * KPAD, bC);
        short* tp = bA; bA = bB; bB = bC; bC = tp;
    }

#pragma unroll
    for (int off = 1; off < 16; off <<= 1)
#pragma unroll
        for (int mi = 0; mi < 4; ++mi)
#pragma unroll
            for (int r = 0; r < 4; ++r)
                zs[mi][r] += __shfl_xor(zs[mi][r], off, 64);
    if (la == 0) {
#pragma unroll
        for (int mi = 0; mi < 4; ++mi)
#pragma unroll
            for (int r = 0; r < 4; ++r) {
                int row = ibase + mi * 16 + g * 4 + r;
                psum[js * NCOL + row] = zs[mi][r];
            }
    }
}

// ---------------- kernel 5: per-row CX-max, per-block max ----------------
__global__ __launch_bounds__(256) void ctx_reduce_kernel(
        const float* __restrict__ rmin, const float* __restrict__ rmax,
        const float* __restrict__ psum, float* __restrict__ blkmax) {
    int tid = threadIdx.x;
    int i = blockIdx.x * 256 + tid;
    float m = rmin[i], M = rmax[i], Z = psum[i];
#pragma unroll
    for (int s = 1; s < JS; ++s) Z += psum[s * NCOL + i];
    float c = 1.0f / (m + EPSILON);
    float w1 = EXP2F(fmaf(M, -Q5L2E * c, Q5L2E));
    float w2 = EXP2F(fmaf(m, -Q5L2E * c, Q5L2E));
    float best = fmaxf(w1, w2) / Z;   // CX strictly positive

    for (int off = 32; off > 0; off >>= 1)
        best = fmaxf(best, __shfl_down(best, off, 64));
    __shared__ float red[4];
    if ((tid & 63) == 0) red[tid >> 6] = best;
    __syncthreads();
    if (tid == 0)
        blkmax[blockIdx.x] = fmaxf(fmaxf(red[0], red[1]), fmaxf(red[2], red[3]));
}

// ---------------- kernel 6: 64 -> 1, -log ----------------
__global__ void ctx_loss_kernel(const float* __restrict__ blkmax,
                                float* __restrict__ out) {
    int tid = threadIdx.x;       // one wave of 64
    float best = blkmax[tid];
    for (int off = 32; off > 0; off >>= 1)
        best = fmaxf(best, __shfl_down(best, off, 64));
    if (tid == 0) out[0] = -logf(best);
}

extern "C" void kernel_launch(void* const* d_in, const int* in_sizes, int n_in,
                              void* d_out, int out_size, void* d_ws, size_t ws_size,
                              hipStream_t stream) {
    const float* inp = (const float*)d_in[0];
    const float* tgt = (const float*)d_in[1];
    float* out = (float*)d_out;

    // ws layout (bytes):
    //   xb     bf16 [16384][64]  2 MB   (linear)
    //   tb     bf16 [16384][64]  2 MB   (slot-swizzled layout)
    //   pmin   f32  [16][16384]  1 MB
    //   pmax   f32  [16][16384]  1 MB
    //   psum   f32  [16][16384]  1 MB
    //   rmin   f32  [16384]      64 KB
    //   rmax   f32  [16384]      64 KB
    //   blkmax f32  [64]
    char* base = (char*)d_ws;
    short* xb     = (short*)(base);
    short* tb     = (short*)(base + (size_t)2 * NCOL * KPAD);           // +2MB
    float* pmin   = (float*)(base + (size_t)4 * NCOL * KPAD);           // +4MB
    float* pmax   = pmin + (size_t)JS * NCOL;
    float* psum   = pmax + (size_t)JS * NCOL;
    float* rmin   = psum + (size_t)JS * NCOL;
    float* rmax   = rmin + NCOL;
    float* blkmax = rmax + NCOL;

    dim3 grid2(NCOL / 256, JS);
    ctx_norm_kernel  <<<NCOL / 256, 256, 0, stream>>>(inp, tgt, xb, tb);
    ctx_stats_kernel <<<grid2, 256, 0, stream>>>(xb, tb, pmin, pmax);
    ctx_fold_kernel  <<<NCOL / 256, 256, 0, stream>>>(pmin, pmax, rmin, rmax);
    ctx_sumexp_kernel<<<grid2, 256, 0, stream>>>(xb, tb, rmin, psum);
    ctx_reduce_kernel<<<NCOL / 256, 256, 0, stream>>>(rmin, rmax, psum, blkmax);
    ctx_loss_kernel  <<<1, 64, 0, stream>>>(blkmax, out);
}

// Round 16
// 100.328 us; speedup vs baseline: 1.0492x; 1.0143x over previous
//
#include <hip/hip_runtime.h>
#include <math.h>

// ContextualLoss via MFMA bf16.
// X,T = reshape(50,16384)[10:50]; S = Xn^T Tn (K=40 padded to 64, bf16 MFMA);
// per input-column i: m=min_j S, M=max_j S, Z=sum_j exp((1-S/(m+eps))/h);
// CXmax_i = max(w(m),w(M))/Z (w monotone in S); loss = -log(max_i CXmax_i).
//
// R16 = R11's PROVEN sync template (reg-staged LDS double buffer,
// issue-early / write-late, one __syncthreads per chunk — passed R11/R12-era
// validation) with parameter-only changes: CHJ 128->64 (LDS 32KB->16KB; 32KB
// capped LDS occupancy at 5 blocks/CU) and JS 16->32 (grid 2048 = 8
// blocks/CU). R15's new protocol (barrier-then-issue + plain syncthreads +
// gll) returned inf — sync-structure edits are new templates (m152); revert
// to known-good and change only parameters. R8's JS=32 null doesn't
// transfer: its mechanism (wave-serial global B-load) is gone with LDS
// staging. xb/tb both LINEAR (reg staging swizzles at ds_write).

#define NCOL   16384
#define KDIM   40
#define KPAD   64
#define ROW0   10
#define EPSILON 1e-5f
#define COS_EPS 1e-8f
#define Q5L2E   7.2134752044448169f   // 5 * log2(e)  (1/h = 5)
#define JS      32                    // j slices
#define JSL     (NCOL / JS)           // 512 j per slice
#define CHJ     64                    // j per staged chunk (8 KB)
#define NCH     (JSL / CHJ)           // 8 chunks per slice
#define TPC     (CHJ / 16)            // 4 16-wide j tiles per chunk

#if __has_builtin(__builtin_amdgcn_exp2f)
#define EXP2F(x) __builtin_amdgcn_exp2f(x)
#else
#define EXP2F(x) __expf((x) * 0.69314718055994531f)
#endif

typedef __attribute__((ext_vector_type(8))) short bf16x8;
typedef __attribute__((ext_vector_type(4))) float f32x4;

static __device__ __forceinline__ unsigned short f2bf(float f) {
    unsigned u = __float_as_uint(f);           // RNE float->bf16
    u += 0x7FFFu + ((u >> 16) & 1u);
    return (unsigned short)(u >> 16);
}

// ---------------- kernel 1: mu + column normalize + bf16 pack ----------------
// xb, tb: linear [n][64] bf16, k-padded with zeros (R11 layout).
__global__ __launch_bounds__(256) void ctx_norm_kernel(
        const float* __restrict__ inp, const float* __restrict__ tgt,
        short* __restrict__ xb, short* __restrict__ tb) {
    int n = blockIdx.x * 256 + threadIdx.x;
    float t[KDIM], x[KDIM];
    float mu = 0.f;
#pragma unroll
    for (int r = 0; r < KDIM; ++r) { t[r] = tgt[(ROW0 + r) * NCOL + n]; mu += t[r]; }
    mu *= (1.0f / KDIM);
    float nt = 0.f;
#pragma unroll
    for (int r = 0; r < KDIM; ++r) { t[r] -= mu; nt = fmaf(t[r], t[r], nt); }
    float rnt = 1.0f / fmaxf(sqrtf(nt), COS_EPS);
    float nx = 0.f;
#pragma unroll
    for (int r = 0; r < KDIM; ++r) {
        x[r] = inp[(ROW0 + r) * NCOL + n] - mu;
        nx = fmaf(x[r], x[r], nx);
    }
    float rnx = 1.0f / fmaxf(sqrtf(nx), COS_EPS);

    short* to = tb + (size_t)n * KPAD;
    short* xo = xb + (size_t)n * KPAD;
#pragma unroll
    for (int q = 0; q < KDIM / 4; ++q) {        // q = 0..9: data
        ushort4 wt, wx;
        wt.x = f2bf(t[4*q+0] * rnt); wt.y = f2bf(t[4*q+1] * rnt);
        wt.z = f2bf(t[4*q+2] * rnt); wt.w = f2bf(t[4*q+3] * rnt);
        wx.x = f2bf(x[4*q+0] * rnx); wx.y = f2bf(x[4*q+1] * rnx);
        wx.z = f2bf(x[4*q+2] * rnx); wx.w = f2bf(x[4*q+3] * rnx);
        *reinterpret_cast<ushort4*>(to + 4*q) = wt;
        *reinterpret_cast<ushort4*>(xo + 4*q) = wx;
    }
    ushort4 z = {0, 0, 0, 0};
#pragma unroll
    for (int q = KDIM / 4; q < KPAD / 4; ++q) { // q = 10..15: zero pad
        *reinterpret_cast<ushort4*>(to + 4*q) = z;
        *reinterpret_cast<ushort4*>(xo + 4*q) = z;
    }
}

// Staging (R11 template, CHJ=64): chunk = 64 rows x 128 B. Thread t moves
// 2 x 16 B: row = t/8 + r*32, slot = t&7. LDS swizzle: phys_slot =
// slot ^ (row & 7) on BOTH ds_write and ds_read (involution, rule #21).
#define STAGE_LOAD(st, src, tid)                                              \
    _Pragma("unroll")                                                         \
    for (int r_ = 0; r_ < 2; ++r_)                                            \
        (st)[r_] = *reinterpret_cast<const bf16x8*>((src) + (tid) * 8 + r_ * 2048);

#define STAGE_WRITE(buf, st, tid)                                             \
    {                                                                         \
        const int row_ = (tid) >> 3, s0_ = (tid) & 7;                         \
        _Pragma("unroll")                                                     \
        for (int r_ = 0; r_ < 2; ++r_) {                                      \
            int rr_ = row_ + r_ * 32;                                         \
            *reinterpret_cast<bf16x8*>(                                       \
                &(buf)[rr_ * 64 + ((s0_ ^ (rr_ & 7)) * 8)]) = (st)[r_];       \
        }                                                                     \
    }

// ---------------- kernel 2: MFMA row min/max over a j slice ----------------
// grid (64, JS), 256 thr = 4 waves. Wave owns 64 i-rows (4 MFMA M-subtiles).
// B double-buffered in LDS (R11 protocol). Read swizzle: slot = g ^ (row&7).
// C/D: col=lane&15, row=(lane>>4)*4+reg.
__global__ __launch_bounds__(256, 4) void ctx_stats_kernel(
        const short* __restrict__ xb, const short* __restrict__ tb,
        float* __restrict__ pmin, float* __restrict__ pmax) {
    const int tid = threadIdx.x;
    const int wave = tid >> 6, l = tid & 63;
    const int la = l & 15, g = l >> 4;
    const int ibase = blockIdx.x * 256 + wave * 64;
    const int js = blockIdx.y;

    __shared__ __align__(16) short ldsb[2][CHJ * KPAD];   // 2 x 8 KB

    bf16x8 a[4][2];
#pragma unroll
    for (int mi = 0; mi < 4; ++mi)
#pragma unroll
        for (int ks = 0; ks < 2; ++ks)
            a[mi][ks] = *reinterpret_cast<const bf16x8*>(
                xb + (size_t)(ibase + mi * 16 + la) * KPAD + ks * 32 + g * 8);

    float vmn[4][4], vmx[4][4];
#pragma unroll
    for (int mi = 0; mi < 4; ++mi)
#pragma unroll
        for (int r = 0; r < 4; ++r) { vmn[mi][r] = 3.4e38f; vmx[mi][r] = -3.4e38f; }

    const short* tbase = tb + (size_t)js * JSL * KPAD;

    {   // prologue: stage chunk 0 into buffer 0
        bf16x8 st[2];
        STAGE_LOAD(st, tbase, tid);
        STAGE_WRITE(ldsb[0], st, tid);
    }
    __syncthreads();

    const f32x4 zero4 = {0.f, 0.f, 0.f, 0.f};
    int cb = 0;
    for (int ch = 0; ch < NCH; ++ch) {
        bf16x8 st[2];
        const bool more = (ch + 1 < NCH);
        if (more) {                       // issue next-chunk loads EARLY
            const short* src = tbase + (size_t)(ch + 1) * CHJ * KPAD;
            STAGE_LOAD(st, src, tid);
        }
#pragma unroll
        for (int jj = 0; jj < TPC; ++jj) {
            const int lr = jj * 16 + la;
            const short* lp = &ldsb[cb][lr * 64];
            bf16x8 b0 = *reinterpret_cast<const bf16x8*>(lp + ((g    ) ^ (lr & 7)) * 8);
            bf16x8 b1 = *reinterpret_cast<const bf16x8*>(lp + ((g + 4) ^ (lr & 7)) * 8);
#pragma unroll
            for (int mi = 0; mi < 4; ++mi) {
                f32x4 acc = __builtin_amdgcn_mfma_f32_16x16x32_bf16(a[mi][0], b0, zero4, 0, 0, 0);
                acc = __builtin_amdgcn_mfma_f32_16x16x32_bf16(a[mi][1], b1, acc, 0, 0, 0);
#pragma unroll
                for (int r = 0; r < 4; ++r) {
                    vmn[mi][r] = fminf(vmn[mi][r], acc[r]);
                    vmx[mi][r] = fmaxf(vmx[mi][r], acc[r]);
                }
            }
        }
        if (more) STAGE_WRITE(ldsb[cb ^ 1], st, tid);   // write LATE
        __syncthreads();
        cb ^= 1;
    }

    // reduce over the 16 column-lanes of each 16-lane group
#pragma unroll
    for (int off = 1; off < 16; off <<= 1)
#pragma unroll
        for (int mi = 0; mi < 4; ++mi)
#pragma unroll
            for (int r = 0; r < 4; ++r) {
                vmn[mi][r] = fminf(vmn[mi][r], __shfl_xor(vmn[mi][r], off, 64));
                vmx[mi][r] = fmaxf(vmx[mi][r], __shfl_xor(vmx[mi][r], off, 64));
            }
    if (la == 0) {
#pragma unroll
        for (int mi = 0; mi < 4; ++mi)
#pragma unroll
            for (int r = 0; r < 4; ++r) {
                int row = ibase + mi * 16 + g * 4 + r;
                pmin[js * NCOL + row] = vmn[mi][r];
                pmax[js * NCOL + row] = vmx[mi][r];
            }
    }
}

// ---------------- kernel 3: fold JS partials -> final row min/max ----------------
__global__ __launch_bounds__(256) void ctx_fold_kernel(
        const float* __restrict__ pmin, const float* __restrict__ pmax,
        float* __restrict__ rmin, float* __restrict__ rmax) {
    int i = blockIdx.x * 256 + threadIdx.x;
    float m = pmin[i], M = pmax[i];
#pragma unroll
    for (int s = 1; s < JS; ++s) {
        m = fminf(m, pmin[s * NCOL + i]);
        M = fmaxf(M, pmax[s * NCOL + i]);
    }
    rmin[i] = m; rmax[i] = M;
}

// ---------------- kernel 4: MFMA row sum of exp over a j slice ----------------
// w = exp((1-S*c)/h) = exp2(fma(S, -Q5L2E*c, Q5L2E)), c = 1/(m+eps) per row.
__global__ __launch_bounds__(256, 4) void ctx_sumexp_kernel(
        const short* __restrict__ xb, const short* __restrict__ tb,
        const float* __restrict__ rmin, float* __restrict__ psum) {
    const int tid = threadIdx.x;
    const int wave = tid >> 6, l = tid & 63;
    const int la = l & 15, g = l >> 4;
    const int ibase = blockIdx.x * 256 + wave * 64;
    const int js = blockIdx.y;

    __shared__ __align__(16) short ldsb[2][CHJ * KPAD];   // 2 x 8 KB

    bf16x8 a[4][2];
#pragma unroll
    for (int mi = 0; mi < 4; ++mi)
#pragma unroll
        for (int ks = 0; ks < 2; ++ks)
            a[mi][ks] = *reinterpret_cast<const bf16x8*>(
                xb + (size_t)(ibase + mi * 16 + la) * KPAD + ks * 32 + g * 8);

    float p[4][4], zs[4][4];
#pragma unroll
    for (int mi = 0; mi < 4; ++mi)
#pragma unroll
        for (int r = 0; r < 4; ++r) {
            int row = ibase + mi * 16 + g * 4 + r;
            float c = 1.0f / (rmin[row] + EPSILON);
            p[mi][r] = -Q5L2E * c;
            zs[mi][r] = 0.f;
        }

    const short* tbase = tb + (size_t)js * JSL * KPAD;

    {   // prologue: stage chunk 0 into buffer 0
        bf16x8 st[2];
        STAGE_LOAD(st, tbase, tid);
        STAGE_WRITE(ldsb[0], st, tid);
    }
    __syncthreads();

    const f32x4 zero4 = {0.f, 0.f, 0.f, 0.f};
    int cb = 0;
    for (int ch = 0; ch < NCH; ++ch) {
        bf16x8 st[2];
        const bool more = (ch + 1 < NCH);
        if (more) {                       // issue next-chunk loads EARLY
            const short* src = tbase + (size_t)(ch + 1) * CHJ * KPAD;
            STAGE_LOAD(st, src, tid);
        }
#pragma unroll
        for (int jj = 0; jj < TPC; ++jj) {
            const int lr = jj * 16 + la;
            const short* lp = &ldsb[cb][lr * 64];
            bf16x8 b0 = *reinterpret_cast<const bf16x8*>(lp + ((g    ) ^ (lr & 7)) * 8);
            bf16x8 b1 = *reinterpret_cast<const bf16x8*>(lp + ((g + 4) ^ (lr & 7)) * 8);
#pragma unroll
            for (int mi = 0; mi < 4; ++mi) {
                f32x4 acc = __builtin_amdgcn_mfma_f32_16x16x32_bf16(a[mi][0], b0, zero4, 0, 0, 0);
                acc = __builtin_amdgcn_mfma_f32_16x16x32_bf16(a[mi][1], b1, acc, 0, 0, 0);
#pragma unroll
                for (int r = 0; r < 4; ++r)
                    zs[mi][r] += EXP2F(fmaf(acc[r], p[mi][r], Q5L2E));
            }
        }
        if (more) STAGE_WRITE(ldsb[cb ^ 1], st, tid);   // write LATE
        __syncthreads();
        cb ^= 1;
    }

#pragma unroll
    for (int off = 1; off < 16; off <<= 1)
#pragma unroll
        for (int mi = 0; mi < 4; ++mi)
#pragma unroll
            for (int r = 0; r < 4; ++r)
                zs[mi][r] += __shfl_xor(zs[mi][r], off, 64);
    if (la == 0) {
#pragma unroll
        for (int mi = 0; mi < 4; ++mi)
#pragma unroll
            for (int r = 0; r < 4; ++r) {
                int row = ibase + mi * 16 + g * 4 + r;
                psum[js * NCOL + row] = zs[mi][r];
            }
    }
}

// ---------------- kernel 5: per-row CX-max, per-block max ----------------
__global__ __launch_bounds__(256) void ctx_reduce_kernel(
        const float* __restrict__ rmin, const float* __restrict__ rmax,
        const float* __restrict__ psum, float* __restrict__ blkmax) {
    int tid = threadIdx.x;
    int i = blockIdx.x * 256 + tid;
    float m = rmin[i], M = rmax[i], Z = psum[i];
#pragma unroll
    for (int s = 1; s < JS; ++s) Z += psum[s * NCOL + i];
    float c = 1.0f / (m + EPSILON);
    float w1 = EXP2F(fmaf(M, -Q5L2E * c, Q5L2E));
    float w2 = EXP2F(fmaf(m, -Q5L2E * c, Q5L2E));
    float best = fmaxf(w1, w2) / Z;   // CX strictly positive

    for (int off = 32; off > 0; off >>= 1)
        best = fmaxf(best, __shfl_down(best, off, 64));
    __shared__ float red[4];
    if ((tid & 63) == 0) red[tid >> 6] = best;
    __syncthreads();
    if (tid == 0)
        blkmax[blockIdx.x] = fmaxf(fmaxf(red[0], red[1]), fmaxf(red[2], red[3]));
}

// ---------------- kernel 6: 64 -> 1, -log ----------------
__global__ void ctx_loss_kernel(const float* __restrict__ blkmax,
                                float* __restrict__ out) {
    int tid = threadIdx.x;       // one wave of 64
    float best = blkmax[tid];
    for (int off = 32; off > 0; off >>= 1)
        best = fmaxf(best, __shfl_down(best, off, 64));
    if (tid == 0) out[0] = -logf(best);
}

extern "C" void kernel_launch(void* const* d_in, const int* in_sizes, int n_in,
                              void* d_out, int out_size, void* d_ws, size_t ws_size,
                              hipStream_t stream) {
    const float* inp = (const float*)d_in[0];
    const float* tgt = (const float*)d_in[1];
    float* out = (float*)d_out;

    // ws layout (bytes):
    //   xb     bf16 [16384][64]  2 MB   (linear)
    //   tb     bf16 [16384][64]  2 MB   (linear)
    //   pmin   f32  [32][16384]  2 MB
    //   pmax   f32  [32][16384]  2 MB
    //   psum   f32  [32][16384]  2 MB
    //   rmin   f32  [16384]      64 KB
    //   rmax   f32  [16384]      64 KB
    //   blkmax f32  [64]
    char* base = (char*)d_ws;
    short* xb     = (short*)(base);
    short* tb     = (short*)(base + (size_t)2 * NCOL * KPAD);           // +2MB
    float* pmin   = (float*)(base + (size_t)4 * NCOL * KPAD);           // +4MB
    float* pmax   = pmin + (size_t)JS * NCOL;
    float* psum   = pmax + (size_t)JS * NCOL;
    float* rmin   = psum + (size_t)JS * NCOL;
    float* rmax   = rmin + NCOL;
    float* blkmax = rmax + NCOL;

    dim3 grid2(NCOL / 256, JS);
    ctx_norm_kernel  <<<NCOL / 256, 256, 0, stream>>>(inp, tgt, xb, tb);
    ctx_stats_kernel <<<grid2, 256, 0, stream>>>(xb, tb, pmin, pmax);
    ctx_fold_kernel  <<<NCOL / 256, 256, 0, stream>>>(pmin, pmax, rmin, rmax);
    ctx_sumexp_kernel<<<grid2, 256, 0, stream>>>(xb, tb, rmin, psum);
    ctx_reduce_kernel<<<NCOL / 256, 256, 0, stream>>>(rmin, rmax, psum, blkmax);
    ctx_loss_kernel  <<<1, 64, 0, stream>>>(blkmax, out);
}

// Round 17
// 94.587 us; speedup vs baseline: 1.1129x; 1.0607x over previous
//
#include <hip/hip_runtime.h>
#include <math.h>

// ContextualLoss via MFMA bf16.
// X,T = reshape(50,16384)[10:50]; S = Xn^T Tn (K=40 padded to 64, bf16 MFMA);
// per input-column i: m=min_j S, M=max_j S, Z=sum_j exp((1-S/(m+eps))/h);
// CXmax_i = max(w(m),w(M))/Z (w monotone in S); loss = -log(max_i CXmax_i).
//
// R17 = R11's proven config exactly (JS=16, CHJ=128, MI_T=4, reg-staged LDS
// double buffer, issue-early/write-late, one __syncthreads per chunk;
// best measured: 94.2 us, sumexp 53.2 @ 85% combined issue) + tail trim:
// fold kernel DELETED -- stats publishes row min/max via deterministic
// atomicMin/Max on order-preserving uint-encoded floats (min/max atomics
// are order-independent => bit-deterministic; float atomicAdd would not
// be). ctx_norm (exactly NCOL threads) re-inits the encoded arrays every
// call, satisfying the no-re-poison rule. Hot-kernel sync structure
// untouched (R15 lesson / m152: sync edits are new templates).

#define NCOL   16384
#define KDIM   40
#define KPAD   64
#define ROW0   10
#define EPSILON 1e-5f
#define COS_EPS 1e-8f
#define Q5L2E   7.2134752044448169f   // 5 * log2(e)  (1/h = 5)
#define JS      16                    // j slices
#define JSL     (NCOL / JS)           // 1024 j per slice
#define CHJ     128                   // j per staged chunk (16 KB)
#define NCH     (JSL / CHJ)           // 8 chunks per slice
#define TPC     (CHJ / 16)            // 8 16-wide j tiles per chunk

#if __has_builtin(__builtin_amdgcn_exp2f)
#define EXP2F(x) __builtin_amdgcn_exp2f(x)
#else
#define EXP2F(x) __expf((x) * 0.69314718055994531f)
#endif

typedef __attribute__((ext_vector_type(8))) short bf16x8;
typedef __attribute__((ext_vector_type(4))) float f32x4;

static __device__ __forceinline__ unsigned short f2bf(float f) {
    unsigned u = __float_as_uint(f);           // RNE float->bf16
    u += 0x7FFFu + ((u >> 16) & 1u);
    return (unsigned short)(u >> 16);
}

// order-preserving float<->uint encoding (f1<f2 <=> enc(f1)<enc(f2) unsigned)
static __device__ __forceinline__ unsigned encf(float f) {
    unsigned b = __float_as_uint(f);
    return (b & 0x80000000u) ? ~b : (b | 0x80000000u);
}
static __device__ __forceinline__ float decf(unsigned u) {
    return __uint_as_float((u & 0x80000000u) ? (u ^ 0x80000000u) : ~u);
}

// ---------------- kernel 1: mu + column normalize + bf16 pack + stat init --
// xb, tb: linear [n][64] bf16, k-padded with zeros (R11 layout).
// Also re-inits rminE/rmaxE (encoded) every call -- one thread per row.
__global__ __launch_bounds__(256) void ctx_norm_kernel(
        const float* __restrict__ inp, const float* __restrict__ tgt,
        short* __restrict__ xb, short* __restrict__ tb,
        unsigned* __restrict__ rminE, unsigned* __restrict__ rmaxE) {
    int n = blockIdx.x * 256 + threadIdx.x;
    rminE[n] = 0xFFFFFFFFu;                    // enc(+inf) upper bound
    rmaxE[n] = 0u;                             // enc(-inf) lower bound
    float t[KDIM], x[KDIM];
    float mu = 0.f;
#pragma unroll
    for (int r = 0; r < KDIM; ++r) { t[r] = tgt[(ROW0 + r) * NCOL + n]; mu += t[r]; }
    mu *= (1.0f / KDIM);
    float nt = 0.f;
#pragma unroll
    for (int r = 0; r < KDIM; ++r) { t[r] -= mu; nt = fmaf(t[r], t[r], nt); }
    float rnt = 1.0f / fmaxf(sqrtf(nt), COS_EPS);
    float nx = 0.f;
#pragma unroll
    for (int r = 0; r < KDIM; ++r) {
        x[r] = inp[(ROW0 + r) * NCOL + n] - mu;
        nx = fmaf(x[r], x[r], nx);
    }
    float rnx = 1.0f / fmaxf(sqrtf(nx), COS_EPS);

    short* to = tb + (size_t)n * KPAD;
    short* xo = xb + (size_t)n * KPAD;
#pragma unroll
    for (int q = 0; q < KDIM / 4; ++q) {        // q = 0..9: data
        ushort4 wt, wx;
        wt.x = f2bf(t[4*q+0] * rnt); wt.y = f2bf(t[4*q+1] * rnt);
        wt.z = f2bf(t[4*q+2] * rnt); wt.w = f2bf(t[4*q+3] * rnt);
        wx.x = f2bf(x[4*q+0] * rnx); wx.y = f2bf(x[4*q+1] * rnx);
        wx.z = f2bf(x[4*q+2] * rnx); wx.w = f2bf(x[4*q+3] * rnx);
        *reinterpret_cast<ushort4*>(to + 4*q) = wt;
        *reinterpret_cast<ushort4*>(xo + 4*q) = wx;
    }
    ushort4 z = {0, 0, 0, 0};
#pragma unroll
    for (int q = KDIM / 4; q < KPAD / 4; ++q) { // q = 10..15: zero pad
        *reinterpret_cast<ushort4*>(to + 4*q) = z;
        *reinterpret_cast<ushort4*>(xo + 4*q) = z;
    }
}

// Staging (R11 template): chunk = CHJ rows x 128 B. Thread t moves 4 x 16 B:
// row = t/8 + r*32, slot = t&7. LDS swizzle: phys_slot = slot ^ (row & 7)
// on BOTH ds_write and ds_read (involution, rule #21).
#define STAGE_LOAD(st, src, tid)                                              \
    _Pragma("unroll")                                                         \
    for (int r_ = 0; r_ < 4; ++r_)                                            \
        (st)[r_] = *reinterpret_cast<const bf16x8*>((src) + (tid) * 8 + r_ * 2048);

#define STAGE_WRITE(buf, st, tid)                                             \
    {                                                                         \
        const int row_ = (tid) >> 3, s0_ = (tid) & 7;                         \
        _Pragma("unroll")                                                     \
        for (int r_ = 0; r_ < 4; ++r_) {                                      \
            int rr_ = row_ + r_ * 32;                                         \
            *reinterpret_cast<bf16x8*>(                                       \
                &(buf)[rr_ * 64 + ((s0_ ^ (rr_ & 7)) * 8)]) = (st)[r_];       \
        }                                                                     \
    }

// ---------------- kernel 2: MFMA row min/max over a j slice ----------------
// grid (64, JS), 256 thr = 4 waves. Wave owns 64 i-rows (4 MFMA M-subtiles).
// B double-buffered in LDS (R11 protocol). Read swizzle: slot = g ^ (row&7).
// C/D: col=lane&15, row=(lane>>4)*4+reg. Publishes via deterministic
// atomicMin/Max on encoded uints (replaces pmin/pmax partials + fold kernel).
__global__ __launch_bounds__(256, 4) void ctx_stats_kernel(
        const short* __restrict__ xb, const short* __restrict__ tb,
        unsigned* __restrict__ rminE, unsigned* __restrict__ rmaxE) {
    const int tid = threadIdx.x;
    const int wave = tid >> 6, l = tid & 63;
    const int la = l & 15, g = l >> 4;
    const int ibase = blockIdx.x * 256 + wave * 64;
    const int js = blockIdx.y;

    __shared__ __align__(16) short ldsb[2][CHJ * KPAD];   // 2 x 16 KB

    bf16x8 a[4][2];
#pragma unroll
    for (int mi = 0; mi < 4; ++mi)
#pragma unroll
        for (int ks = 0; ks < 2; ++ks)
            a[mi][ks] = *reinterpret_cast<const bf16x8*>(
                xb + (size_t)(ibase + mi * 16 + la) * KPAD + ks * 32 + g * 8);

    float vmn[4][4], vmx[4][4];
#pragma unroll
    for (int mi = 0; mi < 4; ++mi)
#pragma unroll
        for (int r = 0; r < 4; ++r) { vmn[mi][r] = 3.4e38f; vmx[mi][r] = -3.4e38f; }

    const short* tbase = tb + (size_t)js * JSL * KPAD;

    {   // prologue: stage chunk 0 into buffer 0
        bf16x8 st[4];
        STAGE_LOAD(st, tbase, tid);
        STAGE_WRITE(ldsb[0], st, tid);
    }
    __syncthreads();

    const f32x4 zero4 = {0.f, 0.f, 0.f, 0.f};
    int cb = 0;
    for (int ch = 0; ch < NCH; ++ch) {
        bf16x8 st[4];
        const bool more = (ch + 1 < NCH);
        if (more) {                       // issue next-chunk loads EARLY
            const short* src = tbase + (size_t)(ch + 1) * CHJ * KPAD;
            STAGE_LOAD(st, src, tid);
        }
#pragma unroll 2
        for (int jj = 0; jj < TPC; ++jj) {
            const int lr = jj * 16 + la;
            const short* lp = &ldsb[cb][lr * 64];
            bf16x8 b0 = *reinterpret_cast<const bf16x8*>(lp + ((g    ) ^ (lr & 7)) * 8);
            bf16x8 b1 = *reinterpret_cast<const bf16x8*>(lp + ((g + 4) ^ (lr & 7)) * 8);
#pragma unroll
            for (int mi = 0; mi < 4; ++mi) {
                f32x4 acc = __builtin_amdgcn_mfma_f32_16x16x32_bf16(a[mi][0], b0, zero4, 0, 0, 0);
                acc = __builtin_amdgcn_mfma_f32_16x16x32_bf16(a[mi][1], b1, acc, 0, 0, 0);
#pragma unroll
                for (int r = 0; r < 4; ++r) {
                    vmn[mi][r] = fminf(vmn[mi][r], acc[r]);
                    vmx[mi][r] = fmaxf(vmx[mi][r], acc[r]);
                }
            }
        }
        if (more) STAGE_WRITE(ldsb[cb ^ 1], st, tid);   // write LATE
        __syncthreads();
        cb ^= 1;
    }

    // reduce over the 16 column-lanes of each 16-lane group
#pragma unroll
    for (int off = 1; off < 16; off <<= 1)
#pragma unroll
        for (int mi = 0; mi < 4; ++mi)
#pragma unroll
            for (int r = 0; r < 4; ++r) {
                vmn[mi][r] = fminf(vmn[mi][r], __shfl_xor(vmn[mi][r], off, 64));
                vmx[mi][r] = fmaxf(vmx[mi][r], __shfl_xor(vmx[mi][r], off, 64));
            }
    if (la == 0) {
#pragma unroll
        for (int mi = 0; mi < 4; ++mi)
#pragma unroll
            for (int r = 0; r < 4; ++r) {
                int row = ibase + mi * 16 + g * 4 + r;
                atomicMin(&rminE[row], encf(vmn[mi][r]));
                atomicMax(&rmaxE[row], encf(vmx[mi][r]));
            }
    }
}

// ---------------- kernel 3: MFMA row sum of exp over a j slice ----------------
// w = exp((1-S*c)/h) = exp2(fma(S, -Q5L2E*c, Q5L2E)), c = 1/(m+eps) per row.
__global__ __launch_bounds__(256, 4) void ctx_sumexp_kernel(
        const short* __restrict__ xb, const short* __restrict__ tb,
        const unsigned* __restrict__ rminE, float* __restrict__ psum) {
    const int tid = threadIdx.x;
    const int wave = tid >> 6, l = tid & 63;
    const int la = l & 15, g = l >> 4;
    const int ibase = blockIdx.x * 256 + wave * 64;
    const int js = blockIdx.y;

    __shared__ __align__(16) short ldsb[2][CHJ * KPAD];   // 2 x 16 KB

    bf16x8 a[4][2];
#pragma unroll
    for (int mi = 0; mi < 4; ++mi)
#pragma unroll
        for (int ks = 0; ks < 2; ++ks)
            a[mi][ks] = *reinterpret_cast<const bf16x8*>(
                xb + (size_t)(ibase + mi * 16 + la) * KPAD + ks * 32 + g * 8);

    float p[4][4], zs[4][4];
#pragma unroll
    for (int mi = 0; mi < 4; ++mi)
#pragma unroll
        for (int r = 0; r < 4; ++r) {
            int row = ibase + mi * 16 + g * 4 + r;
            float c = 1.0f / (decf(rminE[row]) + EPSILON);
            p[mi][r] = -Q5L2E * c;
            zs[mi][r] = 0.f;
        }

    const short* tbase = tb + (size_t)js * JSL * KPAD;

    {   // prologue: stage chunk 0 into buffer 0
        bf16x8 st[4];
        STAGE_LOAD(st, tbase, tid);
        STAGE_WRITE(ldsb[0], st, tid);
    }
    __syncthreads();

    const f32x4 zero4 = {0.f, 0.f, 0.f, 0.f};
    int cb = 0;
    for (int ch = 0; ch < NCH; ++ch) {
        bf16x8 st[4];
        const bool more = (ch + 1 < NCH);
        if (more) {                       // issue next-chunk loads EARLY
            const short* src = tbase + (size_t)(ch + 1) * CHJ * KPAD;
            STAGE_LOAD(st, src, tid);
        }
#pragma unroll 2
        for (int jj = 0; jj < TPC; ++jj) {
            const int lr = jj * 16 + la;
            const short* lp = &ldsb[cb][lr * 64];
            bf16x8 b0 = *reinterpret_cast<const bf16x8*>(lp + ((g    ) ^ (lr & 7)) * 8);
            bf16x8 b1 = *reinterpret_cast<const bf16x8*>(lp + ((g + 4) ^ (lr & 7)) * 8);
#pragma unroll
            for (int mi = 0; mi < 4; ++mi) {
                f32x4 acc = __builtin_amdgcn_mfma_f32_16x16x32_bf16(a[mi][0], b0, zero4, 0, 0, 0);
                acc = __builtin_amdgcn_mfma_f32_16x16x32_bf16(a[mi][1], b1, acc, 0, 0, 0);
#pragma unroll
                for (int r = 0; r < 4; ++r)
                    zs[mi][r] += EXP2F(fmaf(acc[r], p[mi][r], Q5L2E));
            }
        }
        if (more) STAGE_WRITE(ldsb[cb ^ 1], st, tid);   // write LATE
        __syncthreads();
        cb ^= 1;
    }

#pragma unroll
    for (int off = 1; off < 16; off <<= 1)
#pragma unroll
        for (int mi = 0; mi < 4; ++mi)
#pragma unroll
            for (int r = 0; r < 4; ++r)
                zs[mi][r] += __shfl_xor(zs[mi][r], off, 64);
    if (la == 0) {
#pragma unroll
        for (int mi = 0; mi < 4; ++mi)
#pragma unroll
            for (int r = 0; r < 4; ++r) {
                int row = ibase + mi * 16 + g * 4 + r;
                psum[js * NCOL + row] = zs[mi][r];
            }
    }
}

// ---------------- kernel 4: per-row CX-max, per-block max ----------------
__global__ __launch_bounds__(256) void ctx_reduce_kernel(
        const unsigned* __restrict__ rminE, const unsigned* __restrict__ rmaxE,
        const float* __restrict__ psum, float* __restrict__ blkmax) {
    int tid = threadIdx.x;
    int i = blockIdx.x * 256 + tid;
    float m = decf(rminE[i]), M = decf(rmaxE[i]), Z = psum[i];
#pragma unroll
    for (int s = 1; s < JS; ++s) Z += psum[s * NCOL + i];
    float c = 1.0f / (m + EPSILON);
    float w1 = EXP2F(fmaf(M, -Q5L2E * c, Q5L2E));
    float w2 = EXP2F(fmaf(m, -Q5L2E * c, Q5L2E));
    float best = fmaxf(w1, w2) / Z;   // CX strictly positive

    for (int off = 32; off > 0; off >>= 1)
        best = fmaxf(best, __shfl_down(best, off, 64));
    __shared__ float red[4];
    if ((tid & 63) == 0) red[tid >> 6] = best;
    __syncthreads();
    if (tid == 0)
        blkmax[blockIdx.x] = fmaxf(fmaxf(red[0], red[1]), fmaxf(red[2], red[3]));
}

// ---------------- kernel 5: 64 -> 1, -log ----------------
__global__ void ctx_loss_kernel(const float* __restrict__ blkmax,
                                float* __restrict__ out) {
    int tid = threadIdx.x;       // one wave of 64
    float best = blkmax[tid];
    for (int off = 32; off > 0; off >>= 1)
        best = fmaxf(best, __shfl_down(best, off, 64));
    if (tid == 0) out[0] = -logf(best);
}

extern "C" void kernel_launch(void* const* d_in, const int* in_sizes, int n_in,
                              void* d_out, int out_size, void* d_ws, size_t ws_size,
                              hipStream_t stream) {
    const float* inp = (const float*)d_in[0];
    const float* tgt = (const float*)d_in[1];
    float* out = (float*)d_out;

    // ws layout (bytes):
    //   xb     bf16 [16384][64]  2 MB   (linear)
    //   tb     bf16 [16384][64]  2 MB   (linear)
    //   psum   f32  [16][16384]  1 MB
    //   rminE  u32  [16384]      64 KB  (order-preserving encoded)
    //   rmaxE  u32  [16384]      64 KB
    //   blkmax f32  [64]
    char* base = (char*)d_ws;
    short*    xb     = (short*)(base);
    short*    tb     = (short*)(base + (size_t)2 * NCOL * KPAD);        // +2MB
    float*    psum   = (float*)(base + (size_t)4 * NCOL * KPAD);        // +4MB
    unsigned* rminE  = (unsigned*)(psum + (size_t)JS * NCOL);
    unsigned* rmaxE  = rminE + NCOL;
    float*    blkmax = (float*)(rmaxE + NCOL);

    dim3 grid2(NCOL / 256, JS);
    ctx_norm_kernel  <<<NCOL / 256, 256, 0, stream>>>(inp, tgt, xb, tb, rminE, rmaxE);
    ctx_stats_kernel <<<grid2, 256, 0, stream>>>(xb, tb, rminE, rmaxE);
    ctx_sumexp_kernel<<<grid2, 256, 0, stream>>>(xb, tb, rminE, psum);
    ctx_reduce_kernel<<<NCOL / 256, 256, 0, stream>>>(rminE, rmaxE, psum, blkmax);
    ctx_loss_kernel  <<<1, 64, 0, stream>>>(blkmax, out);
}